// Round 4
// baseline (24581.595 us; speedup 1.0000x reference)
//
#include <hip/hip_runtime.h>
#include <stdint.h>

#define T_ 1024

typedef float  floatx4 __attribute__((ext_vector_type(4)));
typedef short  shortx8 __attribute__((ext_vector_type(8)));
typedef unsigned long long u64;

__device__ __forceinline__ unsigned short f2bf(float f) {
  union { float f; unsigned u; } v; v.f = f;
  return (unsigned short)((v.u + 0x7FFFu + ((v.u >> 16) & 1u)) >> 16);
}

// 16B load coherent at agent scope (served from the coherent point / L2-visible)
__device__ __forceinline__ shortx8 ld16_agent(const unsigned short* p) {
  union { u64 q[2]; shortx8 v; } u;
  u.q[0] = __hip_atomic_load((const u64*)p,     __ATOMIC_RELAXED, __HIP_MEMORY_SCOPE_AGENT);
  u.q[1] = __hip_atomic_load(((const u64*)p)+1, __ATOMIC_RELAXED, __HIP_MEMORY_SCOPE_AGENT);
  return u.v;
}

// ---- prep: pack rows [W_hh | W_ih] to bf16, zero epoch counters ----
__global__ void prep_kernel(const float* __restrict__ wih0, const float* __restrict__ whh0,
                            const float* __restrict__ wih1, const float* __restrict__ whh1,
                            unsigned short* __restrict__ wcat0, unsigned short* __restrict__ wcat1,
                            unsigned* __restrict__ f0e, unsigned* __restrict__ f1e) {
  long gid = (long)blockIdx.x * 256 + threadIdx.x;
  if (gid < 1024) f0e[gid] = 0u;
  else if (gid < 2048) f1e[gid - 1024] = 0u;
  const long n0 = 3072L * 1280 / 8;
  const long n1 = 3072L * 2048 / 8;
  union { unsigned short s[8]; uint4 v; } t;
  if (gid < n0) {
    long e = gid * 8; int row = (int)(e / 1280); int k = (int)(e % 1280);
    const float* src = (k < 1024) ? (whh0 + (long)row * 1024 + k)
                                  : (wih0 + (long)row * 256 + (k - 1024));
#pragma unroll
    for (int j = 0; j < 8; ++j) t.s[j] = f2bf(src[j]);
    *(uint4*)(wcat0 + e) = t.v;
  } else if (gid < n0 + n1) {
    long e = (gid - n0) * 8; int row = (int)(e / 2048); int k = (int)(e % 2048);
    const float* src = (k < 1024) ? (whh1 + (long)row * 1024 + k)
                                  : (wih1 + (long)row * 1024 + (k - 1024));
#pragma unroll
    for (int j = 0; j < 8; ++j) t.s[j] = f2bf(src[j]);
    *(uint4*)(wcat1 + e) = t.v;
  }
}

// ---- persistent GRU: 128 blocks/layer, 8 cols/block, weights in LDS ----
template<int L>
__device__ __forceinline__ void gru_body(int lb, int tid,
    const float* __restrict__ x,
    const unsigned short* __restrict__ wcat,
    const float* __restrict__ bihg, const float* __restrict__ bhhg,
    unsigned short* __restrict__ y0ring, unsigned short* __restrict__ h1ring,
    float* __restrict__ dout,
    unsigned* __restrict__ f0e, unsigned* __restrict__ f1e,
    unsigned short* __restrict__ wlds, float (*part)[8][4][16][9])
{
  constexpr int KW  = L ? 2048 : 1280;   // K = [h(1024) | x(1024 or 256)]
  constexpr int WS  = KW + 8;            // padded LDS row stride -> conflict-free ds_read_b128
  constexpr int KTX = L ? 4 : 1;
  constexpr int XW  = L ? 128 : 32;
  const int cb = lb * 8;
  const int w  = tid >> 6;
  const int l  = tid & 63;
  const int lr = l & 15, lq = l >> 4, lc = lr & 7;

  // ---- one-time: stage this block's 24 weight rows into LDS ----
  constexpr int C16 = KW / 8;            // 16B chunks per row
  for (int i = tid; i < 24 * C16; i += 512) {
    int row = i / C16;
    int kk  = (i - row * C16) * 8;
    int g = row >> 3, c = row & 7;
    *(uint4*)(wlds + row * WS + kk) =
        *(const uint4*)(wcat + ((long)g * 1024 + cb + c) * KW + kk);
  }

  const int gb = tid >> 3, gc = tid & 7; // gate thread: batch, col (tid < 128)
  float bir = 0, biz = 0, bin = 0, bhr = 0, bhz = 0, bhn = 0, hp = 0;
  if (tid < 128) {
    bir = bihg[cb + gc];        bhr = bhhg[cb + gc];
    biz = bihg[1024 + cb + gc]; bhz = bhhg[1024 + cb + gc];
    bin = bihg[2048 + cb + gc]; bhn = bhhg[2048 + cb + gc];
  }
  __syncthreads();

  for (int t = 0; t < T_; ++t) {
    // ---- wait: one broadcast dword per condition ----
    for (;;) {
      bool ok = true;
      if constexpr (L == 0) {
        if (t > 0)
          ok &= (__hip_atomic_load(f0e + (t - 1), __ATOMIC_RELAXED, __HIP_MEMORY_SCOPE_AGENT) >= 256u);
        if (t >= 16)
          ok &= (__hip_atomic_load(f1e + (t - 16), __ATOMIC_RELAXED, __HIP_MEMORY_SCOPE_AGENT) >= 256u);
      } else {
        ok &= (__hip_atomic_load(f0e + t, __ATOMIC_RELAXED, __HIP_MEMORY_SCOPE_AGENT) >= 256u);
        if (t > 0)
          ok &= (__hip_atomic_load(f1e + (t - 1), __ATOMIC_RELAXED, __HIP_MEMORY_SCOPE_AGENT) >= 256u);
      }
      if (ok) break;
    }
    asm volatile("" ::: "memory");

    // ---- A-fragments from exchange buffers ----
    floatx4 ar = {0.f, 0.f, 0.f, 0.f};
    floatx4 az = ar, anh = ar, anx = ar;
    shortx8 Ah[4];
    if (t > 0) {
      const unsigned short* hs = L
        ? (h1ring + (((t - 1) & 1) * 16 + lr) * 1024)
        : (y0ring + (((t - 1) & 15) * 16 + lr) * 1024);
#pragma unroll
      for (int kt = 0; kt < 4; ++kt)
        Ah[kt] = ld16_agent(hs + w * 128 + kt * 32 + lq * 8);
    }
    shortx8 Ax[KTX];
    if constexpr (L == 1) {
      const unsigned short* xs = y0ring + ((t & 15) * 16 + lr) * 1024;
#pragma unroll
      for (int kt = 0; kt < 4; ++kt)
        Ax[kt] = ld16_agent(xs + w * 128 + kt * 32 + lq * 8);
    } else {
      const float* xs = x + ((long)lr * T_ + t) * 256 + w * 32 + lq * 8;
      float4 v0 = *(const float4*)xs;
      float4 v1 = *(const float4*)(xs + 4);
      union { unsigned short s[8]; shortx8 v; } u;
      u.s[0] = f2bf(v0.x); u.s[1] = f2bf(v0.y); u.s[2] = f2bf(v0.z); u.s[3] = f2bf(v0.w);
      u.s[4] = f2bf(v1.x); u.s[5] = f2bf(v1.y); u.s[6] = f2bf(v1.z); u.s[7] = f2bf(v1.w);
      Ax[0] = u.v;
    }

    // ---- MFMA with B-fragments streamed from LDS (step-invariant data) ----
    const unsigned short* w0 = wlds + (0  + lc) * WS;
    const unsigned short* w1 = wlds + (8  + lc) * WS;
    const unsigned short* w2 = wlds + (16 + lc) * WS;
    if (t > 0) {
#pragma unroll
      for (int kt = 0; kt < 4; ++kt) {
        const int ko = w * 128 + kt * 32 + lq * 8;
        shortx8 b0 = *(const shortx8*)(w0 + ko);
        shortx8 b1 = *(const shortx8*)(w1 + ko);
        shortx8 b2 = *(const shortx8*)(w2 + ko);
        ar  = __builtin_amdgcn_mfma_f32_16x16x32_bf16(Ah[kt], b0, ar,  0, 0, 0);
        az  = __builtin_amdgcn_mfma_f32_16x16x32_bf16(Ah[kt], b1, az,  0, 0, 0);
        anh = __builtin_amdgcn_mfma_f32_16x16x32_bf16(Ah[kt], b2, anh, 0, 0, 0);
      }
    }
#pragma unroll
    for (int kt = 0; kt < KTX; ++kt) {
      const int ko = 1024 + w * XW + kt * 32 + lq * 8;
      shortx8 b0 = *(const shortx8*)(w0 + ko);
      shortx8 b1 = *(const shortx8*)(w1 + ko);
      shortx8 b2 = *(const shortx8*)(w2 + ko);
      ar  = __builtin_amdgcn_mfma_f32_16x16x32_bf16(Ax[kt], b0, ar,  0, 0, 0);
      az  = __builtin_amdgcn_mfma_f32_16x16x32_bf16(Ax[kt], b1, az,  0, 0, 0);
      anx = __builtin_amdgcn_mfma_f32_16x16x32_bf16(Ax[kt], b2, anx, 0, 0, 0);
    }

    // ---- cross-wave reduce (double-buffered, one barrier per step) ----
    const int par = t & 1;
    if (lr < 8) {
#pragma unroll
      for (int r4 = 0; r4 < 4; ++r4) {
        const int rr = lq * 4 + r4;      // row = batch (m89 layout)
        part[par][w][0][rr][lr] = ar[r4];
        part[par][w][1][rr][lr] = az[r4];
        part[par][w][2][rr][lr] = anh[r4];
        part[par][w][3][rr][lr] = anx[r4];
      }
    }
    __syncthreads();

    if (tid < 128) {
      float sr = 0, sz = 0, snh = 0, snx = 0;
#pragma unroll
      for (int ww = 0; ww < 8; ++ww) {
        sr  += part[par][ww][0][gb][gc];
        sz  += part[par][ww][1][gb][gc];
        snh += part[par][ww][2][gb][gc];
        snx += part[par][ww][3][gb][gc];
      }
      float r = 1.f / (1.f + __expf(-(sr + bir + bhr)));
      float z = 1.f / (1.f + __expf(-(sz + biz + bhz)));
      float targ = snx + bin + r * (snh + bhn);
      float e2 = __expf(2.f * targ);
      float n = 1.f - 2.f / (e2 + 1.f);          // tanh
      float hn = (1.f - z) * n + z * hp;
      hp = hn;
      if (L == 1)
        dout[(long)gb * (T_ * 1024) + (long)t * 1024 + cb + gc] = hn;
      if (t == T_ - 1)
        dout[16777216L + (L ? 16384 : 0) + (long)gb * 1024 + cb + gc] = hn;
      // publish h (bf16 pairs, agent-scope)
      unsigned hv = f2bf(hn);
      unsigned ov = (unsigned)__shfl_xor((int)hv, 1);
      unsigned short* ring = L ? (h1ring + ((t & 1) * 16 + gb) * 1024)
                               : (y0ring + ((t & 15) * 16 + gb) * 1024);
      if ((gc & 1) == 0)
        __hip_atomic_store((unsigned*)(ring + cb + gc), hv | (ov << 16),
                           __ATOMIC_RELAXED, __HIP_MEMORY_SCOPE_AGENT);
      asm volatile("s_waitcnt vmcnt(0)");        // wave-level: all lanes' stores acked
      if (l == 0)
        __hip_atomic_fetch_add((L ? f1e : f0e) + t, 1u,
                               __ATOMIC_RELAXED, __HIP_MEMORY_SCOPE_AGENT);
    }
  }
}

__global__ __launch_bounds__(512) void gru_kernel(
    const float* __restrict__ x,
    const unsigned short* __restrict__ wcat0, const unsigned short* __restrict__ wcat1,
    const float* __restrict__ bih0, const float* __restrict__ bhh0,
    const float* __restrict__ bih1, const float* __restrict__ bhh1,
    unsigned short* y0ring, unsigned short* h1ring, float* dout,
    unsigned* f0e, unsigned* f1e)
{
  __shared__ __align__(16) unsigned short wlds[24 * 2056];   // 98,688 B (L0 uses stride 1288)
  __shared__ float part[2][8][4][16][9];                     // 36,864 B
  const int bid = blockIdx.x, tid = threadIdx.x;
  if (bid < 128)
    gru_body<0>(bid, tid, x, wcat0, bih0, bhh0, y0ring, h1ring, dout, f0e, f1e, wlds, part);
  else
    gru_body<1>(bid - 128, tid, x, wcat1, bih1, bhh1, y0ring, h1ring, dout, f0e, f1e, wlds, part);
}

extern "C" void kernel_launch(void* const* d_in, const int* in_sizes, int n_in,
                              void* d_out, int out_size, void* d_ws, size_t ws_size,
                              hipStream_t stream) {
  (void)in_sizes; (void)n_in; (void)out_size; (void)ws_size;
  const float* x    = (const float*)d_in[0];
  const float* wih0 = (const float*)d_in[2];
  const float* whh0 = (const float*)d_in[3];
  const float* bih0 = (const float*)d_in[4];
  const float* bhh0 = (const float*)d_in[5];
  const float* wih1 = (const float*)d_in[6];
  const float* whh1 = (const float*)d_in[7];
  const float* bih1 = (const float*)d_in[8];
  const float* bhh1 = (const float*)d_in[9];
  char* ws = (char*)d_ws;
  unsigned short* wcat0  = (unsigned short*)(ws + 0L);         //  7,864,320 B
  unsigned short* wcat1  = (unsigned short*)(ws + 7864320L);   // 12,582,912 B
  unsigned short* y0ring = (unsigned short*)(ws + 20447232L);  //    524,288 B (16 slots)
  unsigned short* h1ring = (unsigned short*)(ws + 20971520L);  //     65,536 B (2 slots)
  unsigned* f0e = (unsigned*)(ws + 21037056L);                 //      4,096 B
  unsigned* f1e = (unsigned*)(ws + 21041152L);                 //      4,096 B
  float* out = (float*)d_out;

  prep_kernel<<<4992, 256, 0, stream>>>(wih0, whh0, wih1, whh1, wcat0, wcat1, f0e, f1e);
  gru_kernel<<<256, 512, 0, stream>>>(x, wcat0, wcat1, bih0, bhh0, bih1, bhh1,
                                      y0ring, h1ring, out, f0e, f1e);
}

// Round 5
// 12516.833 us; speedup vs baseline: 1.9639x; 1.9639x over previous
//
#include <hip/hip_runtime.h>
#include <stdint.h>

#define T_ 1024

typedef float  floatx4 __attribute__((ext_vector_type(4)));
typedef short  shortx8 __attribute__((ext_vector_type(8)));
typedef unsigned long long u64;

__device__ __forceinline__ unsigned short f2bf(float f) {
  union { float f; unsigned u; } v; v.f = f;
  return (unsigned short)((v.u + 0x7FFFu + ((v.u >> 16) & 1u)) >> 16);
}

union U8u { unsigned d[4]; shortx8 v; };

__device__ __forceinline__ int min_prog128(const unsigned* prog, int l) {
  int v0 = (int)__hip_atomic_load(prog + l * 16,        __ATOMIC_RELAXED, __HIP_MEMORY_SCOPE_AGENT);
  int v1 = (int)__hip_atomic_load(prog + (l + 64) * 16, __ATOMIC_RELAXED, __HIP_MEMORY_SCOPE_AGENT);
  int m = v0 < v1 ? v0 : v1;
#pragma unroll
  for (int d = 32; d >= 1; d >>= 1) {
    int o = __shfl_xor(m, d);
    m = o < m ? o : m;
  }
  return m;
}

// ---- prep: pack rows [W_hh | W_ih] to bf16; zero tagged rings + progress ----
__global__ void prep_kernel(const float* __restrict__ wih0, const float* __restrict__ whh0,
                            const float* __restrict__ wih1, const float* __restrict__ whh1,
                            unsigned short* __restrict__ wcat0, unsigned short* __restrict__ wcat1,
                            u64* __restrict__ y0ring, u64* __restrict__ h1ring,
                            unsigned* __restrict__ prog1) {
  long gid = (long)blockIdx.x * 256 + threadIdx.x;
  const long n0 = 3072L * 1280 / 8;   // 491,520
  const long n1 = 3072L * 2048 / 8;   // 786,432
  const long npack = n0 + n1;         // 1,277,952
  union { unsigned short s[8]; uint4 v; } t;
  if (gid < n0) {
    long e = gid * 8; int row = (int)(e / 1280); int k = (int)(e % 1280);
    const float* src = (k < 1024) ? (whh0 + (long)row * 1024 + k)
                                  : (wih0 + (long)row * 256 + (k - 1024));
#pragma unroll
    for (int j = 0; j < 8; ++j) t.s[j] = f2bf(src[j]);
    *(uint4*)(wcat0 + e) = t.v;
  } else if (gid < npack) {
    long e = (gid - n0) * 8; int row = (int)(e / 2048); int k = (int)(e % 2048);
    const float* src = (k < 1024) ? (whh1 + (long)row * 1024 + k)
                                  : (wih1 + (long)row * 1024 + (k - 1024));
#pragma unroll
    for (int j = 0; j < 8; ++j) t.s[j] = f2bf(src[j]);
    *(uint4*)(wcat1 + e) = t.v;
  } else {
    long z = gid - npack;
    if (z < 524288) y0ring[z] = 0ull;                       // 64 slots * 16 * 512
    else if (z < 524288 + 131072) h1ring[z - 524288] = 0ull; // 16 slots * 16 * 512
    else if (z < 524288 + 131072 + 2048) prog1[z - 655360] = 0u;
  }
}

// ---- persistent GRU: 128 blocks/layer, 8 cols/block, weights in LDS, tagged exchange ----
template<int L>
__device__ __forceinline__ void gru_body(int lb, int tid,
    const float* __restrict__ x,
    const unsigned short* __restrict__ wcat,
    const float* __restrict__ bihg, const float* __restrict__ bhhg,
    u64* __restrict__ y0ring, u64* __restrict__ h1ring,
    float* __restrict__ dout, unsigned* __restrict__ prog1,
    unsigned short* __restrict__ wlds, float (*part)[8][4][16][9])
{
  constexpr int KW  = L ? 2048 : 1280;   // K = [h(1024) | x(1024 or 256)]
  constexpr int WS  = KW + 8;            // padded LDS row stride
  constexpr int KTX = L ? 4 : 1;
  constexpr int XW  = L ? 128 : 32;
  const int cb = lb * 8;
  const int w  = tid >> 6;
  const int l  = tid & 63;
  const int lr = l & 15, lq = l >> 4, lc = lr & 7;

  // ---- one-time: stage this block's 24 weight rows into LDS ----
  constexpr int C16 = KW / 8;
  for (int i = tid; i < 24 * C16; i += 512) {
    int row = i / C16;
    int kk  = (i - row * C16) * 8;
    int g = row >> 3, c = row & 7;
    *(uint4*)(wlds + row * WS + kk) =
        *(const uint4*)(wcat + ((long)g * 1024 + cb + c) * KW + kk);
  }

  const int gb = tid >> 3, gc = tid & 7;   // gate thread (tid<128): batch, col
  float bir = 0, biz = 0, bin = 0, bhr = 0, bhz = 0, bhn = 0, hp = 0;
  if (tid < 128) {
    bir = bihg[cb + gc];        bhr = bhhg[cb + gc];
    biz = bihg[1024 + cb + gc]; bhz = bhhg[1024 + cb + gc];
    bin = bihg[2048 + cb + gc]; bhn = bhhg[2048 + cb + gc];
  }
  __syncthreads();

  int minp = 0;                            // cached min(prog1) for slot reuse

  for (int t = 0; t < T_; ++t) {
    floatx4 ar = {0.f, 0.f, 0.f, 0.f};
    floatx4 az = ar, anh = ar, anx = ar;

    const unsigned short* w0 = wlds + (0  + lc) * WS;
    const unsigned short* w1 = wlds + (8  + lc) * WS;
    const unsigned short* w2 = wlds + (16 + lc) * WS;

    shortx8 Ah[4];
    bool haveH = (t > 0);

    if constexpr (L == 0) {
      // ---- x-part first (always available): load, convert, MFMA ----
      {
        const float* xs = x + ((long)lr * T_ + t) * 256 + w * 32 + lq * 8;
        float4 v0 = *(const float4*)xs;
        float4 v1 = *(const float4*)(xs + 4);
        union { unsigned short s[8]; shortx8 v; } u;
        u.s[0] = f2bf(v0.x); u.s[1] = f2bf(v0.y); u.s[2] = f2bf(v0.z); u.s[3] = f2bf(v0.w);
        u.s[4] = f2bf(v1.x); u.s[5] = f2bf(v1.y); u.s[6] = f2bf(v1.z); u.s[7] = f2bf(v1.w);
        const int ko = 1024 + w * XW + lq * 8;
        shortx8 b0 = *(const shortx8*)(w0 + ko);
        shortx8 b1 = *(const shortx8*)(w1 + ko);
        shortx8 b2 = *(const shortx8*)(w2 + ko);
        ar  = __builtin_amdgcn_mfma_f32_16x16x32_bf16(u.v, b0, ar,  0, 0, 0);
        az  = __builtin_amdgcn_mfma_f32_16x16x32_bf16(u.v, b1, az,  0, 0, 0);
        anx = __builtin_amdgcn_mfma_f32_16x16x32_bf16(u.v, b2, anx, 0, 0, 0);
      }
      // ---- poll own-layer h = y0[t-1] (tag t), data rides with tag ----
      if (haveH) {
        const u64* bh = y0ring + (((long)((t - 1) & 63) * 16 + lr) * 512);
        const unsigned tg = (unsigned)t;
        u64 q[16];
        for (;;) {
          unsigned bad = 0;
#pragma unroll
          for (int kt = 0; kt < 4; ++kt)
#pragma unroll
            for (int i = 0; i < 4; ++i)
              q[kt * 4 + i] = __hip_atomic_load(bh + w * 64 + kt * 16 + lq * 4 + i,
                                                __ATOMIC_RELAXED, __HIP_MEMORY_SCOPE_AGENT);
#pragma unroll
          for (int i = 0; i < 16; ++i) bad |= ((unsigned)(q[i] >> 32)) ^ tg;
          if (__all(bad == 0)) break;
        }
#pragma unroll
        for (int kt = 0; kt < 4; ++kt) {
          U8u u;
#pragma unroll
          for (int i = 0; i < 4; ++i) u.d[i] = (unsigned)q[kt * 4 + i];
          Ah[kt] = u.v;
        }
      }
    } else {
      // ---- poll h1[t-1] (tag t) and y0[t] (tag t+1) together ----
      const u64* bh = h1ring + (((long)((t - 1) & 15) * 16 + lr) * 512);
      const u64* bx = y0ring + (((long)(t & 63) * 16 + lr) * 512);
      const unsigned tgh = (unsigned)t, tgx = (unsigned)(t + 1);
      u64 qh[16], qx[16];
      for (;;) {
        unsigned bad = 0;
#pragma unroll
        for (int kt = 0; kt < 4; ++kt)
#pragma unroll
          for (int i = 0; i < 4; ++i)
            qx[kt * 4 + i] = __hip_atomic_load(bx + w * 64 + kt * 16 + lq * 4 + i,
                                               __ATOMIC_RELAXED, __HIP_MEMORY_SCOPE_AGENT);
#pragma unroll
        for (int i = 0; i < 16; ++i) bad |= ((unsigned)(qx[i] >> 32)) ^ tgx;
        if (haveH) {
#pragma unroll
          for (int kt = 0; kt < 4; ++kt)
#pragma unroll
            for (int i = 0; i < 4; ++i)
              qh[kt * 4 + i] = __hip_atomic_load(bh + w * 64 + kt * 16 + lq * 4 + i,
                                                 __ATOMIC_RELAXED, __HIP_MEMORY_SCOPE_AGENT);
#pragma unroll
          for (int i = 0; i < 16; ++i) bad |= ((unsigned)(qh[i] >> 32)) ^ tgh;
        }
        if (__all(bad == 0)) break;
      }
      // x-part MFMAs (y0[t] over k = 1024..2047 of K)
#pragma unroll
      for (int kt = 0; kt < 4; ++kt) {
        U8u u;
#pragma unroll
        for (int i = 0; i < 4; ++i) u.d[i] = (unsigned)qx[kt * 4 + i];
        const int ko = 1024 + w * XW + kt * 32 + lq * 8;
        shortx8 b0 = *(const shortx8*)(w0 + ko);
        shortx8 b1 = *(const shortx8*)(w1 + ko);
        shortx8 b2 = *(const shortx8*)(w2 + ko);
        ar  = __builtin_amdgcn_mfma_f32_16x16x32_bf16(u.v, b0, ar,  0, 0, 0);
        az  = __builtin_amdgcn_mfma_f32_16x16x32_bf16(u.v, b1, az,  0, 0, 0);
        anx = __builtin_amdgcn_mfma_f32_16x16x32_bf16(u.v, b2, anx, 0, 0, 0);
      }
      if (haveH) {
#pragma unroll
        for (int kt = 0; kt < 4; ++kt) {
          U8u u;
#pragma unroll
          for (int i = 0; i < 4; ++i) u.d[i] = (unsigned)qh[kt * 4 + i];
          Ah[kt] = u.v;
        }
      }
    }

    // ---- h-part MFMAs ----
    if (haveH) {
#pragma unroll
      for (int kt = 0; kt < 4; ++kt) {
        const int ko = w * 128 + kt * 32 + lq * 8;
        shortx8 b0 = *(const shortx8*)(w0 + ko);
        shortx8 b1 = *(const shortx8*)(w1 + ko);
        shortx8 b2 = *(const shortx8*)(w2 + ko);
        ar  = __builtin_amdgcn_mfma_f32_16x16x32_bf16(Ah[kt], b0, ar,  0, 0, 0);
        az  = __builtin_amdgcn_mfma_f32_16x16x32_bf16(Ah[kt], b1, az,  0, 0, 0);
        anh = __builtin_amdgcn_mfma_f32_16x16x32_bf16(Ah[kt], b2, anh, 0, 0, 0);
      }
    }

    // ---- cross-wave reduce (double-buffered, one barrier per step) ----
    const int par = t & 1;
    if (lr < 8) {
#pragma unroll
      for (int r4 = 0; r4 < 4; ++r4) {
        const int rr = lq * 4 + r4;      // row = batch (m89 layout)
        part[par][w][0][rr][lr] = ar[r4];
        part[par][w][1][rr][lr] = az[r4];
        part[par][w][2][rr][lr] = anh[r4];
        part[par][w][3][rr][lr] = anx[r4];
      }
    }
    __syncthreads();

    if (tid < 128) {
      float sr = 0, sz = 0, snh = 0, snx = 0;
#pragma unroll
      for (int ww = 0; ww < 8; ++ww) {
        sr  += part[par][ww][0][gb][gc];
        sz  += part[par][ww][1][gb][gc];
        snh += part[par][ww][2][gb][gc];
        snx += part[par][ww][3][gb][gc];
      }
      float r = 1.f / (1.f + __expf(-(sr + bir + bhr)));
      float z = 1.f / (1.f + __expf(-(sz + biz + bhz)));
      float targ = snx + bin + r * (snh + bhn);
      float e2 = __expf(2.f * targ);
      float n = 1.f - 2.f / (e2 + 1.f);          // tanh
      float hn = (1.f - z) * n + z * hp;
      hp = hn;

      // ---- slot-reuse back-pressure (provably never spins in steady state) ----
      if constexpr (L == 0) {
        while (minp < t - 63) minp = min_prog128(prog1, l);
      } else {
        while (minp < t - 14) minp = min_prog128(prog1, l);
      }

      // ---- publish: single 8B store carries data + tag (fire-and-forget) ----
      unsigned hv = f2bf(hn);
      unsigned ov = (unsigned)__shfl_xor((int)hv, 1);
      if ((gc & 1) == 0) {
        u64 word = (u64)(hv | (ov << 16)) | ((u64)(unsigned)(t + 1) << 32);
        u64* ring = L ? (h1ring + ((long)(t & 15) * 16 + gb) * 512 + ((cb + gc) >> 1))
                      : (y0ring + ((long)(t & 63) * 16 + gb) * 512 + ((cb + gc) >> 1));
        __hip_atomic_store(ring, word, __ATOMIC_RELAXED, __HIP_MEMORY_SCOPE_AGENT);
      }

      // ---- outputs (off critical path) ----
      if (L == 1)
        dout[(long)gb * (T_ * 1024) + (long)t * 1024 + cb + gc] = hn;
      if (t == T_ - 1)
        dout[16777216L + (L ? 16384 : 0) + (long)gb * 1024 + cb + gc] = hn;

      if (L == 1 && tid == 0)
        __hip_atomic_store(prog1 + lb * 16, (unsigned)(t + 1),
                           __ATOMIC_RELAXED, __HIP_MEMORY_SCOPE_AGENT);
    }
  }
}

__global__ __launch_bounds__(512) void gru_kernel(
    const float* __restrict__ x,
    const unsigned short* __restrict__ wcat0, const unsigned short* __restrict__ wcat1,
    const float* __restrict__ bih0, const float* __restrict__ bhh0,
    const float* __restrict__ bih1, const float* __restrict__ bhh1,
    u64* y0ring, u64* h1ring, float* dout, unsigned* prog1)
{
  __shared__ __align__(16) unsigned short wlds[24 * 2056];   // 98,688 B (L0 uses stride 1288)
  __shared__ float part[2][8][4][16][9];                     // 36,864 B
  const int bid = blockIdx.x, tid = threadIdx.x;
  if (bid < 128)
    gru_body<0>(bid, tid, x, wcat0, bih0, bhh0, y0ring, h1ring, dout, prog1, wlds, part);
  else
    gru_body<1>(bid - 128, tid, x, wcat1, bih1, bhh1, y0ring, h1ring, dout, prog1, wlds, part);
}

extern "C" void kernel_launch(void* const* d_in, const int* in_sizes, int n_in,
                              void* d_out, int out_size, void* d_ws, size_t ws_size,
                              hipStream_t stream) {
  (void)in_sizes; (void)n_in; (void)out_size; (void)ws_size;
  const float* x    = (const float*)d_in[0];
  const float* wih0 = (const float*)d_in[2];
  const float* whh0 = (const float*)d_in[3];
  const float* bih0 = (const float*)d_in[4];
  const float* bhh0 = (const float*)d_in[5];
  const float* wih1 = (const float*)d_in[6];
  const float* whh1 = (const float*)d_in[7];
  const float* bih1 = (const float*)d_in[8];
  const float* bhh1 = (const float*)d_in[9];
  char* ws = (char*)d_ws;
  unsigned short* wcat0 = (unsigned short*)(ws + 0L);          //  7,864,320 B
  unsigned short* wcat1 = (unsigned short*)(ws + 7864320L);    // 12,582,912 B
  u64* y0ring = (u64*)(ws + 20447232L);                        //  4,194,304 B (64 tagged slots)
  u64* h1ring = (u64*)(ws + 24641536L);                        //  1,048,576 B (16 tagged slots)
  unsigned* prog1 = (unsigned*)(ws + 25690112L);               //      8,192 B
  float* out = (float*)d_out;

  prep_kernel<<<7560, 256, 0, stream>>>(wih0, whh0, wih1, whh1, wcat0, wcat1,
                                        y0ring, h1ring, prog1);
  gru_kernel<<<256, 512, 0, stream>>>(x, wcat0, wcat1, bih0, bhh0, bih1, bhh1,
                                      y0ring, h1ring, out, prog1);
}

// Round 6
// 9991.789 us; speedup vs baseline: 2.4602x; 1.2527x over previous
//
#include <hip/hip_runtime.h>
#include <stdint.h>

#define T_ 1024

typedef float  floatx4 __attribute__((ext_vector_type(4)));
typedef short  shortx8 __attribute__((ext_vector_type(8)));
typedef unsigned long long u64;

__device__ __forceinline__ unsigned short f2bf(float f) {
  union { float f; unsigned u; } v; v.f = f;
  return (unsigned short)((v.u + 0x7FFFu + ((v.u >> 16) & 1u)) >> 16);
}

union U8u { unsigned d[4]; shortx8 v; };

// 16B of ring data via 2 agent-coherent u64 loads (p must be 16B-aligned)
__device__ __forceinline__ shortx8 ld16u(const unsigned* p) {
  u64 q0 = __hip_atomic_load((const u64*)p,     __ATOMIC_RELAXED, __HIP_MEMORY_SCOPE_AGENT);
  u64 q1 = __hip_atomic_load((const u64*)p + 1, __ATOMIC_RELAXED, __HIP_MEMORY_SCOPE_AGENT);
  U8u u;
  u.d[0] = (unsigned)q0; u.d[1] = (unsigned)(q0 >> 32);
  u.d[2] = (unsigned)q1; u.d[3] = (unsigned)(q1 >> 32);
  return u.v;
}

// ---- prep: pack rows [W_hh | W_ih] to bf16; zero flags ----
__global__ void prep_kernel(const float* __restrict__ wih0, const float* __restrict__ whh0,
                            const float* __restrict__ wih1, const float* __restrict__ whh1,
                            unsigned short* __restrict__ wcat0, unsigned short* __restrict__ wcat1,
                            unsigned* __restrict__ flags0, unsigned* __restrict__ flags1) {
  long gid = (long)blockIdx.x * 256 + threadIdx.x;
  const long n0 = 3072L * 1280 / 8;   // 491,520
  const long n1 = 3072L * 2048 / 8;   // 786,432
  const long npack = n0 + n1;
  union { unsigned short s[8]; uint4 v; } t;
  if (gid < n0) {
    long e = gid * 8; int row = (int)(e / 1280); int k = (int)(e % 1280);
    const float* src = (k < 1024) ? (whh0 + (long)row * 1024 + k)
                                  : (wih0 + (long)row * 256 + (k - 1024));
#pragma unroll
    for (int j = 0; j < 8; ++j) t.s[j] = f2bf(src[j]);
    *(uint4*)(wcat0 + e) = t.v;
  } else if (gid < npack) {
    long e = (gid - n0) * 8; int row = (int)(e / 2048); int k = (int)(e % 2048);
    const float* src = (k < 1024) ? (whh1 + (long)row * 1024 + k)
                                  : (wih1 + (long)row * 1024 + (k - 1024));
#pragma unroll
    for (int j = 0; j < 8; ++j) t.s[j] = f2bf(src[j]);
    *(uint4*)(wcat1 + e) = t.v;
  } else {
    long z = gid - npack;
    if (z < 2048) flags0[z] = 0u;
    else if (z < 4096) flags1[z - 2048] = 0u;
  }
}

// ---- persistent GRU: 128 blocks/layer, 8 cols/block, weights in LDS, flag protocol ----
template<int L>
__device__ __forceinline__ void gru_body(int lb, int tid,
    const float* __restrict__ x,
    const unsigned short* __restrict__ wcat,
    const float* __restrict__ bihg, const float* __restrict__ bhhg,
    unsigned* __restrict__ y0ring, unsigned* __restrict__ h1ring,
    float* __restrict__ dout,
    unsigned* __restrict__ flags0, unsigned* __restrict__ flags1,
    unsigned short* __restrict__ wlds, float (*part)[8][4][16][9])
{
  constexpr int KW  = L ? 2048 : 1280;   // K = [h(1024) | x(1024 or 256)]
  constexpr int WS  = KW + 8;            // padded LDS row stride
  constexpr int KTX = L ? 4 : 1;
  constexpr int XW  = L ? 128 : 32;
  const int cb = lb * 8;
  const int w  = tid >> 6;
  const int l  = tid & 63;
  const int lr = l & 15, lq = l >> 4, lc = lr & 7;

  // ---- one-time: stage this block's 24 weight rows into LDS ----
  constexpr int C16 = KW / 8;
  for (int i = tid; i < 24 * C16; i += 512) {
    int row = i / C16;
    int kk  = (i - row * C16) * 8;
    int g = row >> 3, c = row & 7;
    *(uint4*)(wlds + row * WS + kk) =
        *(const uint4*)(wcat + ((long)g * 1024 + cb + c) * KW + kk);
  }

  const int gb = tid >> 3, gc = tid & 7;   // gate thread (tid<128): batch, col
  float bir = 0, biz = 0, bin = 0, bhr = 0, bhz = 0, bhn = 0, hp = 0;
  if (tid < 128) {
    bir = bihg[cb + gc];        bhr = bhhg[cb + gc];
    biz = bihg[1024 + cb + gc]; bhz = bhhg[1024 + cb + gc];
    bin = bihg[2048 + cb + gc]; bhn = bhhg[2048 + cb + gc];
  }
  __syncthreads();

  // flag pointers: one u64 (two gate-wave halves) per producer, 64B stride
  const u64* fown = (const u64*)(L ? flags1 : flags0);
  const u64* foth = (const u64*)(L ? flags0 : flags1);
  const u64* pa0 = fown + (long)l * 8;
  const u64* pa1 = fown + (long)(l + 64) * 8;
  const u64* pb0 = foth + (long)l * 8;
  const u64* pb1 = foth + (long)(l + 64) * 8;

  for (int t = 0; t < T_; ++t) {
    floatx4 ar = {0.f, 0.f, 0.f, 0.f};
    floatx4 az = ar, anh = ar, anx = ar;

    const unsigned short* w0 = wlds + (0  + lc) * WS;
    const unsigned short* w1 = wlds + (8  + lc) * WS;
    const unsigned short* w2 = wlds + (16 + lc) * WS;

    if constexpr (L == 0) {
      // x-part first (always available, overlaps the poll below)
      const float* xs = x + ((long)lr * T_ + t) * 256 + w * 32 + lq * 8;
      float4 v0 = *(const float4*)xs;
      float4 v1 = *(const float4*)(xs + 4);
      union { unsigned short s[8]; shortx8 v; } u;
      u.s[0] = f2bf(v0.x); u.s[1] = f2bf(v0.y); u.s[2] = f2bf(v0.z); u.s[3] = f2bf(v0.w);
      u.s[4] = f2bf(v1.x); u.s[5] = f2bf(v1.y); u.s[6] = f2bf(v1.z); u.s[7] = f2bf(v1.w);
      const int ko = 1024 + w * XW + lq * 8;
      shortx8 b0 = *(const shortx8*)(w0 + ko);
      shortx8 b1 = *(const shortx8*)(w1 + ko);
      shortx8 b2 = *(const shortx8*)(w2 + ko);
      ar  = __builtin_amdgcn_mfma_f32_16x16x32_bf16(u.v, b0, ar,  0, 0, 0);
      az  = __builtin_amdgcn_mfma_f32_16x16x32_bf16(u.v, b1, az,  0, 0, 0);
      anx = __builtin_amdgcn_mfma_f32_16x16x32_bf16(u.v, b2, anx, 0, 0, 0);
    }

    // ---- thin detect loop: 4 u64 flag loads per lane per iteration ----
    {
      const int to = t;                         // own-layer h[t-1] available
      const int tx = L ? (t + 1) : (t - 63);    // L1: y0[t] ready; L0: slot freed
      for (;;) {
        u64 a0 = __hip_atomic_load(pa0, __ATOMIC_RELAXED, __HIP_MEMORY_SCOPE_AGENT);
        u64 a1 = __hip_atomic_load(pa1, __ATOMIC_RELAXED, __HIP_MEMORY_SCOPE_AGENT);
        u64 b0 = __hip_atomic_load(pb0, __ATOMIC_RELAXED, __HIP_MEMORY_SCOPE_AGENT);
        u64 b1 = __hip_atomic_load(pb1, __ATOMIC_RELAXED, __HIP_MEMORY_SCOPE_AGENT);
        bool ok = (int)(unsigned)a0 >= to && (int)(a0 >> 32) >= to
               && (int)(unsigned)a1 >= to && (int)(a1 >> 32) >= to
               && (int)(unsigned)b0 >= tx && (int)(b0 >> 32) >= tx
               && (int)(unsigned)b1 >= tx && (int)(b1 >> 32) >= tx;
        if (__all(ok)) break;
      }
    }
    asm volatile("" ::: "memory");

    // ---- bulk data read (once) + MFMAs ----
    const bool haveH = (t > 0);
    shortx8 Ah[4];
    if (haveH) {
      const unsigned* hrow = L
        ? (h1ring + ((long)((t - 1) & 15) * 16 + lr) * 512)
        : (y0ring + ((long)((t - 1) & 63) * 16 + lr) * 512);
#pragma unroll
      for (int kt = 0; kt < 4; ++kt)
        Ah[kt] = ld16u(hrow + w * 64 + kt * 16 + lq * 4);
    }
    if constexpr (L == 1) {
      const unsigned* xrow = y0ring + ((long)(t & 63) * 16 + lr) * 512;
#pragma unroll
      for (int kt = 0; kt < 4; ++kt) {
        shortx8 Ax = ld16u(xrow + w * 64 + kt * 16 + lq * 4);
        const int ko = 1024 + w * XW + kt * 32 + lq * 8;
        shortx8 b0 = *(const shortx8*)(w0 + ko);
        shortx8 b1 = *(const shortx8*)(w1 + ko);
        shortx8 b2 = *(const shortx8*)(w2 + ko);
        ar  = __builtin_amdgcn_mfma_f32_16x16x32_bf16(Ax, b0, ar,  0, 0, 0);
        az  = __builtin_amdgcn_mfma_f32_16x16x32_bf16(Ax, b1, az,  0, 0, 0);
        anx = __builtin_amdgcn_mfma_f32_16x16x32_bf16(Ax, b2, anx, 0, 0, 0);
      }
    }
    if (haveH) {
#pragma unroll
      for (int kt = 0; kt < 4; ++kt) {
        const int ko = w * 128 + kt * 32 + lq * 8;
        shortx8 b0 = *(const shortx8*)(w0 + ko);
        shortx8 b1 = *(const shortx8*)(w1 + ko);
        shortx8 b2 = *(const shortx8*)(w2 + ko);
        ar  = __builtin_amdgcn_mfma_f32_16x16x32_bf16(Ah[kt], b0, ar,  0, 0, 0);
        az  = __builtin_amdgcn_mfma_f32_16x16x32_bf16(Ah[kt], b1, az,  0, 0, 0);
        anh = __builtin_amdgcn_mfma_f32_16x16x32_bf16(Ah[kt], b2, anh, 0, 0, 0);
      }
    }

    // ---- cross-wave reduce (double-buffered, one barrier per step) ----
    const int par = t & 1;
    if (lr < 8) {
#pragma unroll
      for (int r4 = 0; r4 < 4; ++r4) {
        const int rr = lq * 4 + r4;      // row = batch (m89 layout)
        part[par][w][0][rr][lr] = ar[r4];
        part[par][w][1][rr][lr] = az[r4];
        part[par][w][2][rr][lr] = anh[r4];
        part[par][w][3][rr][lr] = anx[r4];
      }
    }
    __syncthreads();

    if (tid < 128) {
      float sr = 0, sz = 0, snh = 0, snx = 0;
#pragma unroll
      for (int ww = 0; ww < 8; ++ww) {
        sr  += part[par][ww][0][gb][gc];
        sz  += part[par][ww][1][gb][gc];
        snh += part[par][ww][2][gb][gc];
        snx += part[par][ww][3][gb][gc];
      }
      float r = 1.f / (1.f + __expf(-(sr + bir + bhr)));
      float z = 1.f / (1.f + __expf(-(sz + biz + bhz)));
      float targ = snx + bin + r * (snh + bhn);
      float e2 = __expf(2.f * targ);
      float n = 1.f - 2.f / (e2 + 1.f);          // tanh
      float hn = (1.f - z) * n + z * hp;
      hp = hn;

      // ---- publish: ring store -> vmcnt(0) -> flag store; dout after ----
      unsigned hv = f2bf(hn);
      unsigned ov = (unsigned)__shfl_xor((int)hv, 1);
      unsigned* ring = L ? (h1ring + ((long)(t & 15) * 16 + gb) * 512 + lb * 4 + (gc >> 1))
                         : (y0ring + ((long)(t & 63) * 16 + gb) * 512 + lb * 4 + (gc >> 1));
      if ((gc & 1) == 0)
        __hip_atomic_store(ring, hv | (ov << 16),
                           __ATOMIC_RELAXED, __HIP_MEMORY_SCOPE_AGENT);
      asm volatile("s_waitcnt vmcnt(0)" ::: "memory");
      if ((tid & 63) == 0) {
        unsigned* fw = (L ? flags1 : flags0) + lb * 16 + (tid >> 6);
        __hip_atomic_store(fw, (unsigned)(t + 1),
                           __ATOMIC_RELAXED, __HIP_MEMORY_SCOPE_AGENT);
      }

      if (L == 1)
        dout[(long)gb * (T_ * 1024) + (long)t * 1024 + cb + gc] = hn;
      if (t == T_ - 1)
        dout[16777216L + (L ? 16384 : 0) + (long)gb * 1024 + cb + gc] = hn;
    }
  }
}

__global__ __launch_bounds__(512) void gru_kernel(
    const float* __restrict__ x,
    const unsigned short* __restrict__ wcat0, const unsigned short* __restrict__ wcat1,
    const float* __restrict__ bih0, const float* __restrict__ bhh0,
    const float* __restrict__ bih1, const float* __restrict__ bhh1,
    unsigned* y0ring, unsigned* h1ring, float* dout,
    unsigned* flags0, unsigned* flags1)
{
  __shared__ __align__(16) unsigned short wlds[24 * 2056];   // 98,688 B (L0 uses stride 1288)
  __shared__ float part[2][8][4][16][9];                     // 36,864 B
  const int bid = blockIdx.x, tid = threadIdx.x;
  if (bid < 128)
    gru_body<0>(bid, tid, x, wcat0, bih0, bhh0, y0ring, h1ring, dout, flags0, flags1, wlds, part);
  else
    gru_body<1>(bid - 128, tid, x, wcat1, bih1, bhh1, y0ring, h1ring, dout, flags0, flags1, wlds, part);
}

extern "C" void kernel_launch(void* const* d_in, const int* in_sizes, int n_in,
                              void* d_out, int out_size, void* d_ws, size_t ws_size,
                              hipStream_t stream) {
  (void)in_sizes; (void)n_in; (void)out_size; (void)ws_size;
  const float* x    = (const float*)d_in[0];
  const float* wih0 = (const float*)d_in[2];
  const float* whh0 = (const float*)d_in[3];
  const float* bih0 = (const float*)d_in[4];
  const float* bhh0 = (const float*)d_in[5];
  const float* wih1 = (const float*)d_in[6];
  const float* whh1 = (const float*)d_in[7];
  const float* bih1 = (const float*)d_in[8];
  const float* bhh1 = (const float*)d_in[9];
  char* ws = (char*)d_ws;
  unsigned short* wcat0 = (unsigned short*)(ws + 0L);          //  7,864,320 B
  unsigned short* wcat1 = (unsigned short*)(ws + 7864320L);    // 12,582,912 B
  unsigned* y0ring = (unsigned*)(ws + 20447232L);              //  2,097,152 B (64 slots)
  unsigned* h1ring = (unsigned*)(ws + 22544384L);              //    524,288 B (16 slots)
  unsigned* flags0 = (unsigned*)(ws + 23068672L);              //      8,192 B
  unsigned* flags1 = (unsigned*)(ws + 23076864L);              //      8,192 B
  float* out = (float*)d_out;

  prep_kernel<<<5008, 256, 0, stream>>>(wih0, whh0, wih1, whh1, wcat0, wcat1,
                                        flags0, flags1);
  gru_kernel<<<256, 512, 0, stream>>>(x, wcat0, wcat1, bih0, bhh0, bih1, bhh1,
                                      y0ring, h1ring, out, flags0, flags1);
}